// Round 4
// baseline (462.941 us; speedup 1.0000x reference)
//
#include <hip/hip_runtime.h>
#include <stdint.h>
#include <math.h>

typedef __attribute__((ext_vector_type(4))) int i32x4;

#define GLD16(gp, lp)                                                     \
  __builtin_amdgcn_global_load_lds(                                       \
      (__attribute__((address_space(1))) void*)(gp),                      \
      (__attribute__((address_space(3))) void*)(lp), 16, 0, 0)

// ---------- prep W: qw = rintf(clip(w*127)) -> int8  (fp32 = np-exact)
__global__ void __launch_bounds__(256) k_prep_w(const float* __restrict__ wx,
                                                const float* __restrict__ wh,
                                                signed char* __restrict__ Wq) {
  int i = blockIdx.x * 256 + threadIdx.x;
  int e = i << 2;
  int g = e >> 12;
  int c = e & 4095;
  const float* src = (c < 2048) ? (wx + g * 2048 + c) : (wh + g * 2048 + (c - 2048));
  float4 v = *(const float4*)src;
  char4 o;
  o.x = (signed char)(int)rintf(fminf(fmaxf(v.x * 127.0f, -127.0f), 127.0f));
  o.y = (signed char)(int)rintf(fminf(fmaxf(v.y * 127.0f, -127.0f), 127.0f));
  o.z = (signed char)(int)rintf(fminf(fmaxf(v.z * 127.0f, -127.0f), 127.0f));
  o.w = (signed char)(int)rintf(fminf(fmaxf(v.w * 127.0f, -127.0f), 127.0f));
  *(char4*)(Wq + e) = o;
}

// ---------- prep A: Aq[1024][12288] = [d5|d4|d3|d2|d1|qx] int8
// hx = d1*2^-4 + d2*2^-11 + d3*2^-18 + d4*2^-25 + d5*2^-32 (exact in fp32:
// pow2 scales are exact; each subtraction spans <=24 mantissa bits)
__global__ void __launch_bounds__(256) k_prep_a(const float* __restrict__ x,
                                                const float* __restrict__ hx,
                                                signed char* __restrict__ Aq) {
  int i = blockIdx.x * 256 + threadIdx.x;
  int e = i << 2;
  int b = e >> 11;
  int c = e & 2047;
  float4 xv = *(const float4*)(x + b * 2048 + c);
  float4 hv = *(const float4*)(hx + b * 2048 + c);
  float xa[4] = {xv.x, xv.y, xv.z, xv.w};
  float ha[4] = {hv.x, hv.y, hv.z, hv.w};
  char4 q4, s1, s2, s3, s4, s5;
  signed char* qp = (signed char*)&q4;
  signed char* p1 = (signed char*)&s1;
  signed char* p2 = (signed char*)&s2;
  signed char* p3 = (signed char*)&s3;
  signed char* p4 = (signed char*)&s4;
  signed char* p5 = (signed char*)&s5;
  #pragma unroll
  for (int j = 0; j < 4; ++j) {
    qp[j] = (signed char)(int)rintf(fminf(fmaxf(xa[j] * 127.0f, -127.0f), 127.0f));
    float r = ha[j];
    float d1 = rintf(r * 0x1p4f);    r -= d1 * 0x1p-4f;
    float d2 = rintf(r * 0x1p11f);   r -= d2 * 0x1p-11f;
    float d3 = rintf(r * 0x1p18f);   r -= d3 * 0x1p-18f;
    float d4 = rintf(r * 0x1p25f);   r -= d4 * 0x1p-25f;
    float d5 = rintf(r * 0x1p32f);
    p1[j] = (signed char)(int)d1;
    p2[j] = (signed char)(int)d2;
    p3[j] = (signed char)(int)d3;
    p4[j] = (signed char)(int)d4;
    p5[j] = (signed char)(int)d5;
  }
  size_t base = (size_t)b * 12288;
  *(char4*)(Aq + base + 0 * 2048 + c) = s5;
  *(char4*)(Aq + base + 1 * 2048 + c) = s4;
  *(char4*)(Aq + base + 2 * 2048 + c) = s3;
  *(char4*)(Aq + base + 3 * 2048 + c) = s2;
  *(char4*)(Aq + base + 4 * 2048 + c) = s1;
  *(char4*)(Aq + base + 5 * 2048 + c) = q4;   // phase 5: qx
}

// ---------- fused exact i8 GEMM + LSTM epilogue ----------
// Block tile 128m x 128n (4 gates x 32 j), BK=256. 4 waves 2x2, wave tile
// 64x64 (4x4 of 16x16x64 i8 MFMA). 6 phases x 8 iters. Exact i32 phase sums,
// exact fp64 Horner fold (47-bit span < 53). LDS rows 256 B, 16-chunk XOR
// swizzle p = c ^ (row&15): conflict-free b128 reads. fp64 epilogue.
__global__ void __launch_bounds__(256, 1) k_gemm_lstm(
    const signed char* __restrict__ Aq, const signed char* __restrict__ Wq,
    const float* __restrict__ bx, const float* __restrict__ bh,
    const float* __restrict__ cx, float* __restrict__ out) {
  __shared__ __align__(16) signed char smem[65536];
  signed char* As = smem;            // [128][256] i8
  signed char* Bs = smem + 32768;    // [128][256] i8

  const int t  = threadIdx.x;
  const int wv = t >> 6;
  const int ln = t & 63;
  const int wm = wv & 1;
  const int wn = wv >> 1;
  const int lr = ln & 15;
  const int q  = ln >> 4;

  const int j0 = blockIdx.x * 32;
  const int m0 = blockIdx.y * 128;

  // staging source offsets: statement i, slot s = i*256+t; row r = s>>4,
  // position p = s&15 holds logical chunk c = p ^ (r&15)
  int sA[8], sB[8];
  #pragma unroll
  for (int i = 0; i < 8; ++i) {
    int s = i * 256 + t;
    int r = s >> 4;
    int p = s & 15;
    int c = p ^ (r & 15);
    sA[i] = (m0 + r) * 12288 + c * 16;
    int gate = r >> 5;
    int jj = r & 31;
    sB[i] = (gate * 2048 + j0 + jj) * 4096 + c * 16;
  }

  // LDS read offsets: frag(row, kst): chunk c = kst*4+q, p = c ^ lr
  int aoff[4], boff[4];
  #pragma unroll
  for (int f = 0; f < 4; ++f) {
    aoff[f] = (wm * 64 + f * 16 + lr) * 256;
    boff[f] = 32768 + (wn * 64 + f * 16 + lr) * 256;
  }

  i32x4 acc[4][4];
  double Hd[4][4][4];
  #pragma unroll
  for (int mf = 0; mf < 4; ++mf)
    #pragma unroll
    for (int nf = 0; nf < 4; ++nf)
      acc[mf][nf] = (i32x4){0, 0, 0, 0};

  #pragma unroll 1
  for (int ph = 0; ph < 6; ++ph) {
    const int kA = ph * 2048;
    const int kB = (ph < 5) ? 2048 : 0;
    #pragma unroll 1
    for (int it = 0; it < 8; ++it) {
      const int kk = it * 256;
      __syncthreads();
      #pragma unroll
      for (int i = 0; i < 8; ++i)
        GLD16(Aq + sA[i] + kA + kk, As + i * 4096 + wv * 1024);
      #pragma unroll
      for (int i = 0; i < 8; ++i)
        GLD16(Wq + sB[i] + kB + kk, Bs + i * 4096 + wv * 1024);
      asm volatile("s_waitcnt vmcnt(0)" ::: "memory");
      __syncthreads();
      #pragma unroll
      for (int kst = 0; kst < 4; ++kst) {
        const int poff = ((kst * 4 + q) ^ lr) * 16;
        i32x4 af[4], bf[4];
        #pragma unroll
        for (int mf = 0; mf < 4; ++mf) af[mf] = *(const i32x4*)&As[aoff[mf] + poff];
        #pragma unroll
        for (int nf = 0; nf < 4; ++nf) bf[nf] = *(const i32x4*)&smem[boff[nf] + poff];
        #pragma unroll
        for (int mf = 0; mf < 4; ++mf)
          #pragma unroll
          for (int nf = 0; nf < 4; ++nf)
            acc[mf][nf] = __builtin_amdgcn_mfma_i32_16x16x64_i8(
                af[mf], bf[nf], acc[mf][nf], 0, 0, 0);
      }
    }
    if (ph < 5) {   // exact fp64 Horner fold of digit-phase sums
      #pragma unroll
      for (int mf = 0; mf < 4; ++mf)
        #pragma unroll
        for (int nf = 0; nf < 4; ++nf) {
          #pragma unroll
          for (int r = 0; r < 4; ++r) {
            double S = (double)acc[mf][nf][r];
            Hd[mf][nf][r] = (ph == 0) ? S : Hd[mf][nf][r] * 0x1p-7 + S;
          }
          acc[mf][nf] = (i32x4){0, 0, 0, 0};
        }
    }
  }
  // acc = exact Sx; Hd = S_d1 + S_d2*2^-7 + ... + S_d5*2^-28 (exact)

  const double invsq = 1.0 / 16129.0;
  const double hsc   = 0x1p-4 / 127.0;

  float (*Lgo)[128][33] = (float(*)[128][33])smem;

  __syncthreads();
  if (wn == 1) {   // gates g (nf 0,1), o (nf 2,3): activate, stash q*127
    #pragma unroll
    for (int mf = 0; mf < 4; ++mf) {
      #pragma unroll
      for (int nf = 0; nf < 4; ++nf) {
        int gate = 2 + (nf >> 1);
        int jj = (nf & 1) * 16 + lr;
        int gcol = gate * 2048 + j0 + jj;
        double bsum = (double)bx[gcol] + (double)bh[gcol];
        #pragma unroll
        for (int r = 0; r < 4; ++r) {
          double pre = (double)acc[mf][nf][r] * invsq + Hd[mf][nf][r] * hsc + bsum;
          double av = (gate == 2) ? tanh(pre) : (1.0 / (1.0 + exp(-pre)));
          double qv = rint(fmin(fmax(av * 127.0, -127.0), 127.0));
          int m = wm * 64 + mf * 16 + q * 4 + r;
          Lgo[gate - 2][m][jj] = (float)qv;
        }
      }
    }
  }
  __syncthreads();
  if (wn == 0) {   // gates f (nf 0,1), i (nf 2,3): combine + store
    #pragma unroll
    for (int mf = 0; mf < 4; ++mf) {
      #pragma unroll
      for (int nfp = 0; nfp < 2; ++nfp) {
        int jj = nfp * 16 + lr;
        int gcf = j0 + jj;
        int gci = 2048 + j0 + jj;
        double bf_ = (double)bx[gcf] + (double)bh[gcf];
        double bi_ = (double)bx[gci] + (double)bh[gci];
        #pragma unroll
        for (int r = 0; r < 4; ++r) {
          int m = wm * 64 + mf * 16 + q * 4 + r;
          double fpre = (double)acc[mf][nfp][r] * invsq + Hd[mf][nfp][r] * hsc + bf_;
          double ipre = (double)acc[mf][nfp + 2][r] * invsq + Hd[mf][nfp + 2][r] * hsc + bi_;
          double fv = rint(fmin(fmax((1.0 / (1.0 + exp(-fpre))) * 127.0, -127.0), 127.0)) / 127.0;
          double iv = rint(fmin(fmax((1.0 / (1.0 + exp(-ipre))) * 127.0, -127.0), 127.0)) / 127.0;
          double gv = (double)Lgo[0][m][jj] / 127.0;
          double ov = (double)Lgo[1][m][jj] / 127.0;
          int row = m0 + m;
          int col = j0 + jj;
          double cn = fv * (double)cx[row * 2048 + col] + iv * gv;
          double tq = rint(fmin(fmax(tanh(cn) * 127.0, -127.0), 127.0)) / 127.0;
          double hv = ov * tq;
          double cq = rint(fmin(fmax(cn * 127.0, -127.0), 127.0)) / 127.0;
          out[row * 2048 + col] = (float)hv;
          out[2097152 + row * 2048 + col] = (float)cq;
        }
      }
    }
  }
}

// ---------- launch ----------
extern "C" void kernel_launch(void* const* d_in, const int* in_sizes, int n_in,
                              void* d_out, int out_size, void* d_ws, size_t ws_size,
                              hipStream_t stream) {
  const float* x  = (const float*)d_in[0];
  const float* hx = (const float*)d_in[1];
  const float* cx = (const float*)d_in[2];
  const float* wx = (const float*)d_in[3];
  const float* bx = (const float*)d_in[4];
  const float* wh = (const float*)d_in[5];
  const float* bh = (const float*)d_in[6];
  float* out = (float*)d_out;

  signed char* Wq = (signed char*)d_ws;               // 33,554,432 B
  signed char* Aq = (signed char*)d_ws + 33554432;    // 12,582,912 B

  k_prep_w<<<dim3(32768), dim3(256), 0, stream>>>(wx, wh, Wq);
  k_prep_a<<<dim3(2048), dim3(256), 0, stream>>>(x, hx, Aq);
  k_gemm_lstm<<<dim3(64, 8), dim3(256), 0, stream>>>(Aq, Wq, bx, bh, cx, out);
}